// Round 2
// baseline (168.929 us; speedup 1.0000x reference)
//
#include <hip/hip_runtime.h>

// ShiftLayer: out[b,t,c] = in[b, t+off[c], c], off per c%3 = {0: identity, 1: t-1, 2: t+1},
// zero padding at t boundaries. B=8, L=8192, C=384 (divisible by 3), fp32 in/out.
//
// One thread per float4 (4 channels = 16B). Load the matching 16B slot from rows
// t-1, t, t+1 (zeros at the sequence edges) and select per component by channel%3.
// Coalesced 16B/lane loads/stores; pure memory-roofline kernel (~201 MB total).

constexpr int kB = 8;
constexpr int kL = 8192;
constexpr int kC = 384;
constexpr int kV = 4;                   // fp32 elements per 16B vector
constexpr int kCV = kC / kV;            // 96 vectors per (b,t) row
constexpr int kTotalV = kB * kL * kCV;  // 6,291,456 vectors

typedef __attribute__((ext_vector_type(4))) float f32x4;

__global__ __launch_bounds__(256) void ShiftLayer_66932770341347_kernel(
    const f32x4* __restrict__ in, f32x4* __restrict__ out) {
  int idx = blockIdx.x * 256 + threadIdx.x;
  if (idx >= kTotalV) return;

  int v = idx % kCV;              // vector index within the channel row
  int t = (idx / kCV) % kL;       // time index

  const f32x4 zero = {0.f, 0.f, 0.f, 0.f};
  f32x4 cur = in[idx];
  f32x4 prev = (t > 0)      ? in[idx - kCV] : zero;
  f32x4 next = (t < kL - 1) ? in[idx + kCV] : zero;

  // Base channel of this vector: c0 = v*4; c0 % 3 == v % 3 (since 4 ≡ 1 mod 3).
  int m0 = v % 3;

  f32x4 o;
#pragma unroll
  for (int i = 0; i < kV; ++i) {
    int m = m0 + i;
    m = (m >= 3) ? m - 3 : m;     // (v + i) % 3 without a divide
    m = (m >= 3) ? m - 3 : m;     // i can be up to 3, so m0+i <= 5
    // m==0 -> identity (cur), m==1 -> read t-1 (prev), m==2 -> read t+1 (next)
    o[i] = (m == 0) ? cur[i] : ((m == 1) ? prev[i] : next[i]);
  }
  out[idx] = o;
}

extern "C" void kernel_launch(void* const* d_in, const int* in_sizes, int n_in,
                              void* d_out, int out_size, void* d_ws, size_t ws_size,
                              hipStream_t stream) {
  const f32x4* in = reinterpret_cast<const f32x4*>(d_in[0]);
  f32x4* out = reinterpret_cast<f32x4*>(d_out);

  constexpr int kThreads = 256;
  constexpr int kBlocks = (kTotalV + kThreads - 1) / kThreads;  // 24576
  ShiftLayer_66932770341347_kernel<<<kBlocks, kThreads, 0, stream>>>(in, out);
}